// Round 14
// baseline (106.121 us; speedup 1.0000x reference)
//
#include <hip/hip_runtime.h>
#include <hip/hip_bf16.h>

#define L_SEQ 4096
#define E_DIM 512
#define NHEAD 8
#define DHEAD 64
#define NBATCH 4
#define NROWS (NBATCH * L_SEQ)   // 16384

typedef short bf16x8 __attribute__((ext_vector_type(8)));
typedef float f32x4 __attribute__((ext_vector_type(4)));

__device__ __forceinline__ float bf2f(ushort u) {
    union { float f; unsigned int i; } x;
    x.i = ((unsigned int)u) << 16;
    return x.f;
}
__device__ __forceinline__ ushort f2bf(float f) {
    unsigned int u = __float_as_uint(f);
    unsigned int r = 0x7fffu + ((u >> 16) & 1u);
    u += r;
    return (ushort)(u >> 16);
}

#define GLD16(gptr, lptr) \
    __builtin_amdgcn_global_load_lds( \
        (const __attribute__((address_space(1))) void*)(gptr), \
        (__attribute__((address_space(3))) void*)(lptr), 16, 0, 0)

#define BAR_LGKM() do { \
    asm volatile("s_waitcnt lgkmcnt(0)" ::: "memory"); \
    __builtin_amdgcn_sched_barrier(0); \
    __builtin_amdgcn_s_barrier(); \
    __builtin_amdgcn_sched_barrier(0); } while (0)

// ---------------- weights conversion + sin/cos tables ----------------
__global__ __launch_bounds__(256) void convert_w_kernel(
    const float* __restrict__ w0, const float* __restrict__ w1,
    const float* __restrict__ w2, const float* __restrict__ w3,
    ushort* __restrict__ o0, ushort* __restrict__ o1,
    ushort* __restrict__ o2, ushort* __restrict__ o3,
    float* __restrict__ sintab, float* __restrict__ costab)
{
    const int tid = threadIdx.x;
    const int y = blockIdx.y;
    if (y == 4) {
        const int l = blockIdx.x * 256 + tid;
        if (blockIdx.x < 16) {
            const float ang = (float)(l + 1) * (1.5707963267948966f / (float)L_SEQ);
            sintab[l] = sinf(ang);
            costab[l] = cosf(ang);
        }
        return;
    }
    const float* in = (y == 0) ? w0 : (y == 1) ? w1 : (y == 2) ? w2 : w3;
    ushort* out = (y == 0) ? o0 : (y == 1) ? o1 : (y == 2) ? o2 : o3;
    const int i = blockIdx.x * 256 + tid;
    float4 f = reinterpret_cast<const float4*>(in)[i];
    ushort4 o;
    o.x = f2bf(f.x); o.y = f2bf(f.y); o.z = f2bf(f.z); o.w = f2bf(f.w);
    reinterpret_cast<ushort4*>(out)[i] = o;
}

// ---------------- QKV GEMM: A = x (f32!) staged via GLD16, cvt at frag-read --------
// Eliminates the separate x->bf16 convert pass (100MB traffic). BK=32.
// LDS: dbuf 2 x (A-f32 16KB | B-bf16 8KB) = 48KB -> 3 blocks/CU; TS 34.8KB overlay.
// grid (128, 12): panel on x, mode = y>>2, colBase = (y&3)*128.
// mode 0 (Q): relu -> qb bf16 [l][e];  mode 1 (K): relu -> kT[bh][k][l]
// mode 2 (V): -> vT[bh][d][l]
// A swizzle (128B rows, 8 slots of 16B): slot s holds source chunk s^(r&7);
//   frag (k=g*8..g*8+7 f32) reads slots (2g)^(r&7), (2g+1)^(r&7)  -> 2-way max.
// B swizzle (64B rows, 4 slots): slot s holds chunk s^((r>>1)&3); read g^((fr>>1)&3).
// f2bf here is RNE — bit-identical to the deleted convert kernel.
__global__ __launch_bounds__(256, 3) void qkv8_kernel(
    const float* __restrict__ X,
    const ushort* __restrict__ wq, const ushort* __restrict__ wk, const ushort* __restrict__ wv,
    const float* __restrict__ bq, const float* __restrict__ bk, const float* __restrict__ bv,
    ushort* __restrict__ qb, ushort* __restrict__ kT, ushort* __restrict__ vT)
{
    __shared__ ushort SH[24576];        // 49152 B: buf0 [A16K|B8K] buf1 [A16K|B8K]; TS overlay
    ushort* TS = SH;                    // TS[128][136] = 34816 B

    const int tid = threadIdx.x;
    const int lane = tid & 63;
    const int wid = tid >> 6;
    const int wm = wid >> 1;            // 0..1
    const int wn = wid & 1;             // 0..1
    const int rowBase = blockIdx.x * 128;
    const int mode = blockIdx.y >> 2;
    const int colBase = (blockIdx.y & 3) * 128;

    const ushort* __restrict__ W = (mode == 0) ? wq : (mode == 1) ? wk : wv;
    const float* __restrict__ bias = (mode == 0) ? bq : (mode == 1) ? bk : bv;

    const int fr = lane & 15;
    const int g = lane >> 4;

    f32x4 acc[4][4];
#pragma unroll
    for (int m = 0; m < 4; ++m)
#pragma unroll
        for (int n = 0; n < 4; ++n)
            acc[m][n] = (f32x4){0.f, 0.f, 0.f, 0.f};

    auto STAGE = [&](int kt) {
        const int k0 = kt * 32;
        char* bufc = (char*)SH + (kt & 1) * 24576;
        // A: f32 tile 128x32 = 1024 x 16B chunks
#pragma unroll
        for (int i = 0; i < 4; ++i) {
            const int c = i * 256 + tid;
            const int row = c >> 3;            // 0..127
            const int slot = c & 7;
            const int src = (slot ^ (row & 7)) * 4;   // f32 index
            GLD16(&X[(size_t)(rowBase + row) * E_DIM + k0 + src],
                  bufc + (row * 32 + slot * 4) * 4);
        }
        // B: bf16 tile 128x32 = 512 x 16B chunks
#pragma unroll
        for (int i = 0; i < 2; ++i) {
            const int c = i * 256 + tid;
            const int row = c >> 2;
            const int slot = c & 3;
            const int src = (slot ^ ((row >> 1) & 3)) * 8;
            GLD16(&W[(size_t)(colBase + row) * E_DIM + k0 + src],
                  bufc + 16384 + (row * 32 + slot * 8) * 2);
        }
    };

    STAGE(0);
    STAGE(1);
    asm volatile("s_waitcnt vmcnt(6)" ::: "memory");
    __builtin_amdgcn_sched_barrier(0);
    __builtin_amdgcn_s_barrier();
    __builtin_amdgcn_sched_barrier(0);

    const int b = rowBase >> 12;
    const int lloc = rowBase & (L_SEQ - 1);

    for (int gt = 0; gt < 16; ++gt) {
        const char* bufc = (const char*)SH + (gt & 1) * 24576;
        const float* Af = (const float*)bufc;
        const ushort* Bf = (const ushort*)(bufc + 16384);

        f32x4 alo[4], ahi[4];
        bf16x8 bfv[4];
#pragma unroll
        for (int m = 0; m < 4; ++m) {
            const int r = wm * 64 + m * 16 + fr;
            const int s0 = (2 * g) ^ (r & 7);
            const int s1 = (2 * g + 1) ^ (r & 7);
            alo[m] = *reinterpret_cast<const f32x4*>(&Af[r * 32 + s0 * 4]);
            ahi[m] = *reinterpret_cast<const f32x4*>(&Af[r * 32 + s1 * 4]);
        }
#pragma unroll
        for (int n = 0; n < 4; ++n) {
            const int r = wn * 64 + n * 16 + fr;
            const int sl = g ^ ((r >> 1) & 3);
            bfv[n] = *reinterpret_cast<const bf16x8*>(&Bf[r * 32 + sl * 8]);
        }
        BAR_LGKM();

        if (gt + 2 < 16) STAGE(gt + 2);

        bf16x8 af[4];
#pragma unroll
        for (int m = 0; m < 4; ++m) {
            const int hilo = g & 1;  // chunk 2g covers k g*8..g*8+3; 2g+1 covers +4..7
#pragma unroll
            for (int e = 0; e < 4; ++e) {
                af[m][e]     = (short)f2bf(alo[m][e]);
                af[m][e + 4] = (short)f2bf(ahi[m][e]);
            }
            (void)hilo;
        }

        __builtin_amdgcn_s_setprio(1);
#pragma unroll
        for (int m = 0; m < 4; ++m)
#pragma unroll
            for (int n = 0; n < 4; ++n)
                acc[m][n] = __builtin_amdgcn_mfma_f32_16x16x32_bf16(
                    af[m], bfv[n], acc[m][n], 0, 0, 0);
        __builtin_amdgcn_s_setprio(0);
        __builtin_amdgcn_sched_barrier(0);

        if (gt < 15) {
            if (gt + 2 < 16) asm volatile("s_waitcnt vmcnt(6)" ::: "memory");
            else             asm volatile("s_waitcnt vmcnt(0)" ::: "memory");
            __builtin_amdgcn_sched_barrier(0);
            __builtin_amdgcn_s_barrier();
            __builtin_amdgcn_sched_barrier(0);
        }
    }

    // ---------------- epilogues ----------------
    if (mode == 0) {
#pragma unroll
        for (int m = 0; m < 4; ++m)
#pragma unroll
            for (int j = 0; j < 4; ++j) {
                const int grow = rowBase + wm * 64 + m * 16 + g * 4 + j;
#pragma unroll
                for (int n = 0; n < 4; ++n) {
                    const int gcol = colBase + wn * 64 + n * 16 + fr;
                    const float val = fmaxf(acc[m][n][j] + bias[gcol], 0.f);
                    qb[(size_t)grow * E_DIM + gcol] = f2bf(val);
                }
            }
    } else {
        ushort* __restrict__ dstbuf = (mode == 1) ? kT : vT;
        __syncthreads();                 // all waves done with SH buffers
#pragma unroll
        for (int m = 0; m < 4; ++m)
#pragma unroll
            for (int j = 0; j < 4; ++j) {
                const int lr_ = wm * 64 + m * 16 + g * 4 + j;
#pragma unroll
                for (int n = 0; n < 4; ++n) {
                    const int fcl = wn * 64 + n * 16 + fr;
                    float val = acc[m][n][j] + bias[colBase + fcl];
                    if (mode == 1) val = fmaxf(val, 0.f);
                    TS[fcl * 136 + lr_] = f2bf(val);
                }
            }
        __syncthreads();
#pragma unroll
        for (int i = 0; i < 8; ++i) {
            const int c = i * 256 + tid;
            const int r = c >> 4;              // local feature 0..127
            const int cc = c & 15;             // 16B chunk along l
            const size_t dst = ((size_t)(b * E_DIM + colBase + r)) * L_SEQ + lloc + cc * 8;
            *reinterpret_cast<uint4*>(&dstbuf[dst]) =
                *reinterpret_cast<const uint4*>(&TS[r * 136 + cc * 8]);
        }
    }
}

// ---------------- out GEMM (r12-verified gemm6, mode 3 only): 128x128, BK=64, 2/CU --
__global__ __launch_bounds__(256, 2) void out_gemm_kernel(
    const ushort* __restrict__ A, const ushort* __restrict__ W,
    const float* __restrict__ bias, float* __restrict__ outF)
{
    __shared__ ushort SH[32768];        // 64KB: 2 x (A 16KB | B 16KB)

    const int tid = threadIdx.x;
    const int lane = tid & 63;
    const int wid = tid >> 6;
    const int wm = wid >> 1;
    const int wn = wid & 1;
    const int rowBase = blockIdx.x * 128;
    const int colBase = blockIdx.y * 128;

    const int fr = lane & 15;
    const int g = lane >> 4;
    const int fr7 = fr & 7;
    const int sc_row = tid >> 3;
    const int sc_c16 = tid & 7;

    f32x4 acc[4][4];
#pragma unroll
    for (int m = 0; m < 4; ++m)
#pragma unroll
        for (int n = 0; n < 4; ++n)
            acc[m][n] = (f32x4){0.f, 0.f, 0.f, 0.f};

    auto STAGE = [&](int kt) {
        const int k0 = kt * 64;
        const int bufb = (kt & 1) * 16384;
#pragma unroll
        for (int i = 0; i < 4; ++i) {
            const int row = i * 32 + sc_row;
            const int srcc = (sc_c16 ^ (row & 7)) * 8;
            GLD16(&A[(size_t)(rowBase + row) * E_DIM + k0 + srcc],
                  &SH[bufb + row * 64 + sc_c16 * 8]);
        }
#pragma unroll
        for (int i = 0; i < 4; ++i) {
            const int row = i * 32 + sc_row;
            const int srcc = (sc_c16 ^ (row & 7)) * 8;
            GLD16(&W[(size_t)(colBase + row) * E_DIM + k0 + srcc],
                  &SH[bufb + 8192 + row * 64 + sc_c16 * 8]);
        }
    };

    STAGE(0);
    STAGE(1);
    asm volatile("s_waitcnt vmcnt(8)" ::: "memory");
    __builtin_amdgcn_sched_barrier(0);
    __builtin_amdgcn_s_barrier();
    __builtin_amdgcn_sched_barrier(0);

    const int kch0 = (g ^ fr7) * 8;
    const int kch1 = ((4 + g) ^ fr7) * 8;
    const int aroff = (wm * 64 + fr) * 64;
    const int broff = 8192 + (wn * 64 + fr) * 64;

    for (int gt = 0; gt < 8; ++gt) {
        const int base = (gt & 1) * 16384;
        bf16x8 af[2][4], bfv[2][4];
#pragma unroll
        for (int m = 0; m < 4; ++m) {
            af[0][m] = *reinterpret_cast<const bf16x8*>(&SH[base + aroff + m * 1024 + kch0]);
            af[1][m] = *reinterpret_cast<const bf16x8*>(&SH[base + aroff + m * 1024 + kch1]);
        }
#pragma unroll
        for (int n = 0; n < 4; ++n) {
            bfv[0][n] = *reinterpret_cast<const bf16x8*>(&SH[base + broff + n * 1024 + kch0]);
            bfv[1][n] = *reinterpret_cast<const bf16x8*>(&SH[base + broff + n * 1024 + kch1]);
        }
        BAR_LGKM();

        if (gt + 2 < 8) STAGE(gt + 2);

        __builtin_amdgcn_s_setprio(1);
#pragma unroll
        for (int kk = 0; kk < 2; ++kk)
#pragma unroll
            for (int m = 0; m < 4; ++m)
#pragma unroll
                for (int n = 0; n < 4; ++n)
                    acc[m][n] = __builtin_amdgcn_mfma_f32_16x16x32_bf16(
                        af[kk][m], bfv[kk][n], acc[m][n], 0, 0, 0);
        __builtin_amdgcn_s_setprio(0);
        __builtin_amdgcn_sched_barrier(0);

        if (gt < 7) {
            if (gt + 2 < 8) asm volatile("s_waitcnt vmcnt(8)" ::: "memory");
            else            asm volatile("s_waitcnt vmcnt(0)" ::: "memory");
            __builtin_amdgcn_sched_barrier(0);
            __builtin_amdgcn_s_barrier();
            __builtin_amdgcn_sched_barrier(0);
        }
    }

#pragma unroll
    for (int m = 0; m < 4; ++m)
#pragma unroll
        for (int j = 0; j < 4; ++j) {
            const int grow = rowBase + wm * 64 + m * 16 + g * 4 + j;
#pragma unroll
            for (int n = 0; n < 4; ++n) {
                const int gcol = colBase + wn * 64 + n * 16 + fr;
                outF[(size_t)grow * E_DIM + gcol] = acc[m][n][j] + bias[gcol];
            }
        }
}

// ---------------- kv via MFMA, fused cos/sin from tables, no LDS ----------------
__global__ __launch_bounds__(256) void kv_kernel(
    const ushort* __restrict__ kT, const ushort* __restrict__ vT,
    const float* __restrict__ sintab, const float* __restrict__ costab,
    float* __restrict__ kv_part, float* __restrict__ sum_part)
{
    const int chunk = blockIdx.x;   // 0..7
    const int bh = blockIdx.y;      // 0..31
    const int tid = threadIdx.x;
    const int lane = tid & 63;
    const int w = tid >> 6;
    const int fr = lane & 15;
    const int g = lane >> 4;

    const size_t tbase = (size_t)bh * 64 * L_SEQ;

    f32x4 acc[8], accS[8];
#pragma unroll
    for (int n = 0; n < 8; ++n) {
        acc[n] = (f32x4){0.f, 0.f, 0.f, 0.f};
        accS[n] = (f32x4){0.f, 0.f, 0.f, 0.f};
    }

    const int lchunk = chunk * (L_SEQ / 8);
    for (int l0 = lchunk; l0 < lchunk + (L_SEQ / 8); l0 += 32) {
        const int col = l0 + g * 8;
        bf16x8 vf = *reinterpret_cast<const bf16x8*>(&vT[tbase + (size_t)(w * 16 + fr) * L_SEQ + col]);
        bf16x8 kf[4];
#pragma unroll
        for (int n = 0; n < 4; ++n)
            kf[n] = *reinterpret_cast<const bf16x8*>(&kT[tbase + (size_t)(n * 16 + fr) * L_SEQ + col]);
        float4 c0 = *reinterpret_cast<const float4*>(&costab[col]);
        float4 c1 = *reinterpret_cast<const float4*>(&costab[col + 4]);
        float4 s0 = *reinterpret_cast<const float4*>(&sintab[col]);
        float4 s1 = *reinterpret_cast<const float4*>(&sintab[col + 4]);
        const float c8[8] = {c0.x, c0.y, c0.z, c0.w, c1.x, c1.y, c1.z, c1.w};
        const float s8[8] = {s0.x, s0.y, s0.z, s0.w, s1.x, s1.y, s1.z, s1.w};
        bf16x8 afc, afs, cw, sw;
#pragma unroll
        for (int e = 0; e < 8; ++e) {
            const float v = bf2f((ushort)vf[e]);
            afc[e] = (short)f2bf(v * c8[e]);
            afs[e] = (short)f2bf(v * s8[e]);
            cw[e]  = (short)f2bf(c8[e]);
            sw[e]  = (short)f2bf(s8[e]);
        }
#pragma unroll
        for (int n = 0; n < 4; ++n) {
            acc[n]      = __builtin_amdgcn_mfma_f32_16x16x32_bf16(afc, kf[n], acc[n], 0, 0, 0);
            acc[n + 4]  = __builtin_amdgcn_mfma_f32_16x16x32_bf16(afs, kf[n], acc[n + 4], 0, 0, 0);
            accS[n]     = __builtin_amdgcn_mfma_f32_16x16x32_bf16(cw,  kf[n], accS[n], 0, 0, 0);
            accS[n + 4] = __builtin_amdgcn_mfma_f32_16x16x32_bf16(sw,  kf[n], accS[n + 4], 0, 0, 0);
        }
    }

    const size_t pbase = ((size_t)(chunk * 32 + bh)) * 8192;
#pragma unroll
    for (int n = 0; n < 8; ++n)
#pragma unroll
        for (int j = 0; j < 4; ++j)
            kv_part[pbase + (size_t)(w * 16 + g * 4 + j) * 128 + n * 16 + fr] = acc[n][j];
    if (w == 0 && g == 0) {
        const size_t sbase = (size_t)(chunk * 32 + bh) * 128;
#pragma unroll
        for (int n = 0; n < 8; ++n)
            sum_part[sbase + n * 16 + fr] = accS[n][0];
    }
}

// ---------------- reduce partials; emit bf16 kvT_ext[bh][80][128] ----------------
#define KVT_ROWS 80
#define KVT_STRIDE (KVT_ROWS * 128)
__global__ __launch_bounds__(256) void kv_reduce_kernel(
    const float* __restrict__ kv_part, const float* __restrict__ sum_part,
    ushort* __restrict__ kvT)
{
    const int bh = blockIdx.x;
    const int tid = threadIdx.x;
    ushort* kvb = kvT + (size_t)bh * KVT_STRIDE;
    for (int idx = tid; idx < 8192; idx += 256) {
        float s = 0.f;
#pragma unroll
        for (int c = 0; c < 8; ++c)
            s += kv_part[((size_t)(c * 32 + bh)) * 8192 + idx];
        kvb[idx] = f2bf(s);
    }
    if (tid < 128) {
        float s = 0.f;
#pragma unroll
        for (int c = 0; c < 8; ++c)
            s += sum_part[(size_t)(c * 32 + bh) * 128 + tid];
        const ushort hi = f2bf(s);
        const float lo = s - bf2f(hi);
        kvb[64 * 128 + tid] = hi;
        kvb[65 * 128 + tid] = f2bf(lo);
    }
    for (int idx = tid; idx < 14 * 128; idx += 256)
        kvb[66 * 128 + idx] = 0;
}

// ---------------- attention via MFMA: A-fragments scaled by cos/sin on the fly -------
__global__ __launch_bounds__(256) void attn_kernel(
    const ushort* __restrict__ Qb, const ushort* __restrict__ kvT,
    const float* __restrict__ sintab, const float* __restrict__ costab,
    ushort* __restrict__ attn_out)
{
    const int bh = blockIdx.y;
    const int b = bh >> 3, h = bh & 7;
    const int tid = threadIdx.x;
    const int lane = tid & 63;
    const int w = tid >> 6;

    __shared__ ushort Bs[KVT_ROWS][136];

#pragma unroll
    for (int i = 0; i < 5; ++i) {
        const int c = i * 256 + tid;
        const int d = c >> 4, cc = c & 15;
        *reinterpret_cast<uint4*>(&Bs[d][cc * 8]) =
            *reinterpret_cast<const uint4*>(&kvT[(size_t)bh * KVT_STRIDE + (size_t)c * 8]);
    }
    __syncthreads();

    const int rowBase = blockIdx.x * 256 + w * 64;
    const int fr = lane & 15;
    const int g = lane >> 4;

    float cvm[4], svm[4];
#pragma unroll
    for (int m = 0; m < 4; ++m) {
        const int l = (rowBase + m * 16 + fr) & (L_SEQ - 1);
        cvm[m] = costab[l];
        svm[m] = sintab[l];
    }

    f32x4 acc[4][5];
#pragma unroll
    for (int m = 0; m < 4; ++m)
#pragma unroll
        for (int n = 0; n < 5; ++n)
            acc[m][n] = (f32x4){0.f, 0.f, 0.f, 0.f};

#pragma unroll
    for (int ks = 0; ks < 4; ++ks) {
        const int kk = (ks & 1) * 32 + g * 8;
        const int kcomb = ks * 32 + g * 8;

        bf16x8 af[4];
#pragma unroll
        for (int m = 0; m < 4; ++m) {
            const int r = rowBase + m * 16 + fr;
            bf16x8 qf = *reinterpret_cast<const bf16x8*>(
                &Qb[((size_t)(b * L_SEQ) + r) * E_DIM + h * DHEAD + kk]);
            const float sc = (ks < 2) ? cvm[m] : svm[m];
#pragma unroll
            for (int e = 0; e < 8; ++e)
                af[m][e] = (short)f2bf(bf2f((ushort)qf[e]) * sc);
        }

        bf16x8 bfr[5];
#pragma unroll
        for (int n = 0; n < 5; ++n)
            bfr[n] = *reinterpret_cast<const bf16x8*>(&Bs[n * 16 + fr][kcomb]);
#pragma unroll
        for (int m = 0; m < 4; ++m)
#pragma unroll
            for (int n = 0; n < 5; ++n)
                acc[m][n] = __builtin_amdgcn_mfma_f32_16x16x32_bf16(af[m], bfr[n], acc[m][n], 0, 0, 0);
    }

#pragma unroll
    for (int m = 0; m < 4; ++m) {
#pragma unroll
        for (int j = 0; j < 4; ++j) {
            const float den = __shfl(acc[m][4][j], g * 16 + 0) + __shfl(acc[m][4][j], g * 16 + 1);
            const float z = 1.f / fmaxf(den, 1e-6f);
            const int grow = rowBase + m * 16 + g * 4 + j;
            const size_t obase = ((size_t)(b * L_SEQ) + grow) * E_DIM + h * DHEAD;
#pragma unroll
            for (int n = 0; n < 4; ++n)
                attn_out[obase + n * 16 + fr] = f2bf(acc[m][n][j] * z);
        }
    }
}

// ---------------- launch ----------------
extern "C" void kernel_launch(void* const* d_in, const int* in_sizes, int n_in,
                              void* d_out, int out_size, void* d_ws, size_t ws_size,
                              hipStream_t stream) {
    const float* x  = (const float*)d_in[0];
    const float* Wq = (const float*)d_in[1];
    const float* bq = (const float*)d_in[2];
    const float* Wk = (const float*)d_in[3];
    const float* bk = (const float*)d_in[4];
    const float* Wv = (const float*)d_in[5];
    const float* bv = (const float*)d_in[6];
    const float* Wo = (const float*)d_in[7];
    const float* bo = (const float*)d_in[8];
    float* out = (float*)d_out;

    char* ws = (char*)d_ws;
    size_t off = 0;
    auto alloc = [&](size_t bytes) -> char* {
        char* p = ws + off;
        off += (bytes + 255) & ~(size_t)255;
        return p;
    };

    const size_t big = (size_t)NROWS * E_DIM * sizeof(ushort);   // 16.8 MB
    ushort* wqb = (ushort*)alloc(512 * 512 * sizeof(ushort));
    ushort* wkb = (ushort*)alloc(512 * 512 * sizeof(ushort));
    ushort* wvb = (ushort*)alloc(512 * 512 * sizeof(ushort));
    ushort* wob = (ushort*)alloc(512 * 512 * sizeof(ushort));
    ushort* qb  = (ushort*)alloc(big);   // relu(q), [l][e]
    ushort* kT  = (ushort*)alloc(big);   // relu(k) transposed [bh][k][l]
    ushort* vT  = (ushort*)alloc(big);   // v transposed [bh][d][l]
    float* kv_part  = (float*)alloc((size_t)8 * 32 * 8192 * sizeof(float));
    float* sum_part = (float*)alloc((size_t)8 * 32 * 128 * sizeof(float));
    ushort* kvT     = (ushort*)alloc((size_t)32 * KVT_STRIDE * sizeof(ushort));
    float* sintab   = (float*)alloc(L_SEQ * sizeof(float));
    float* costab   = (float*)alloc(L_SEQ * sizeof(float));
    ushort* attnb = kT;  // kT consumed by kv_kernel before attn_kernel writes

    convert_w_kernel<<<dim3(256, 5), 256, 0, stream>>>(
        Wq, Wk, Wv, Wo, wqb, wkb, wvb, wob, sintab, costab);

    // QKV: reads x f32 directly (no convert pass); mode-major grid, 3 blocks/CU
    qkv8_kernel<<<dim3(128, 12), 256, 0, stream>>>(
        x, wqb, wkb, wvb, bq, bk, bv, qb, kT, vT);

    kv_kernel<<<dim3(8, 32), 256, 0, stream>>>(kT, vT, sintab, costab, kv_part, sum_part);
    kv_reduce_kernel<<<32, 256, 0, stream>>>(kv_part, sum_part, kvT);

    attn_kernel<<<dim3(16, 32), 256, 0, stream>>>(qb, kvT, sintab, costab, attnb);

    out_gemm_kernel<<<dim3(128, 4), 256, 0, stream>>>(attnb, wob, bo, out);
}

// Round 15
// 95.660 us; speedup vs baseline: 1.1094x; 1.1094x over previous
//
#include <hip/hip_runtime.h>
#include <hip/hip_bf16.h>

#define L_SEQ 4096
#define E_DIM 512
#define NHEAD 8
#define DHEAD 64
#define NBATCH 4
#define NROWS (NBATCH * L_SEQ)   // 16384

typedef short bf16x8 __attribute__((ext_vector_type(8)));
typedef float f32x4 __attribute__((ext_vector_type(4)));

__device__ __forceinline__ float bf2f(ushort u) {
    union { float f; unsigned int i; } x;
    x.i = ((unsigned int)u) << 16;
    return x.f;
}
__device__ __forceinline__ ushort f2bf(float f) {
    unsigned int u = __float_as_uint(f);
    unsigned int r = 0x7fffu + ((u >> 16) & 1u);
    u += r;
    return (ushort)(u >> 16);
}

#define GLD16(gptr, lptr) \
    __builtin_amdgcn_global_load_lds( \
        (const __attribute__((address_space(1))) void*)(gptr), \
        (__attribute__((address_space(3))) void*)(lptr), 16, 0, 0)

#define BAR_LGKM() do { \
    asm volatile("s_waitcnt lgkmcnt(0)" ::: "memory"); \
    __builtin_amdgcn_sched_barrier(0); \
    __builtin_amdgcn_s_barrier(); \
    __builtin_amdgcn_sched_barrier(0); } while (0)

// ---------------- fused conversions: x -> bf16, W -> bf16, sin/cos tables ----------
// grid 3088 x 256: blocks [0,2048) convert x (grid-stride); [2048,3072) convert the
// four weights (1 float4/thread); [3072,3088) fill sin/cos tables.
__global__ __launch_bounds__(256) void convert_all_kernel(
    const float* __restrict__ x, ushort* __restrict__ xb,
    const float* __restrict__ w0, const float* __restrict__ w1,
    const float* __restrict__ w2, const float* __restrict__ w3,
    ushort* __restrict__ o0, ushort* __restrict__ o1,
    ushort* __restrict__ o2, ushort* __restrict__ o3,
    float* __restrict__ sintab, float* __restrict__ costab)
{
    const int tid = threadIdx.x;
    const int bid = blockIdx.x;
    if (bid < 2048) {
        const int n4 = NROWS * E_DIM / 4;
        for (int i = bid * 256 + tid; i < n4; i += 2048 * 256) {
            float4 f = reinterpret_cast<const float4*>(x)[i];
            ushort4 o;
            o.x = f2bf(f.x); o.y = f2bf(f.y); o.z = f2bf(f.z); o.w = f2bf(f.w);
            reinterpret_cast<ushort4*>(xb)[i] = o;
        }
    } else if (bid < 3072) {
        const int wb = bid - 2048;            // 0..1023
        const int y = wb >> 8;                // weight 0..3
        const int i = (wb & 255) * 256 + tid; // 0..65535
        const float* in = (y == 0) ? w0 : (y == 1) ? w1 : (y == 2) ? w2 : w3;
        ushort* out = (y == 0) ? o0 : (y == 1) ? o1 : (y == 2) ? o2 : o3;
        float4 f = reinterpret_cast<const float4*>(in)[i];
        ushort4 o;
        o.x = f2bf(f.x); o.y = f2bf(f.y); o.z = f2bf(f.z); o.w = f2bf(f.w);
        reinterpret_cast<ushort4*>(out)[i] = o;
    } else {
        const int l = (bid - 3072) * 256 + tid;
        const float ang = (float)(l + 1) * (1.5707963267948966f / (float)L_SEQ);
        sintab[l] = sinf(ang);
        costab[l] = cosf(ang);
    }
}

// ---------------- pipelined GEMM: 128x128 tile, BK=64, dbuf, 2 blocks/CU ----------
// (r12-verified structure — session best.)
// 256 threads (2x2 waves, wave-tile 64x64). LDS = 2 x (A 16KB | B 16KB) = 64KB ->
// TWO independent blocks per CU: one block's MFMA covers the other's barrier/drain.
// QKV variant (MODE_BASE 0): grid (128, 12); mode = y>>2, colBase = (y&3)*128.
// OUT variant (MODE_BASE 3): grid (128, 4); colBase = y*128.
// mode 0 (Q): relu -> qb bf16 [l][e];  mode 1 (K): relu -> kT[bh][k][l]
// mode 2 (V): -> vT[bh][d][l];         mode 3 (O): -> outF fp32 [l][e]
// Swizzle (r6-verified): slot c16 holds source chunk c16^(row&7); read (kk*4+g)^(fr&7).
// Schedule (r7-verified): reads -> lgkm0+barA -> STAGE(t+2) -> MFMA -> vmcnt(8)+barB.
template<int MODE_BASE>
__global__ __launch_bounds__(256, 2) void gemm6_kernel(
    const ushort* __restrict__ A,
    const ushort* __restrict__ wq, const ushort* __restrict__ wk,
    const ushort* __restrict__ wv, const ushort* __restrict__ wo,
    const float* __restrict__ bq, const float* __restrict__ bk,
    const float* __restrict__ bv, const float* __restrict__ bo,
    ushort* __restrict__ qb, ushort* __restrict__ kT, ushort* __restrict__ vT,
    float* __restrict__ outF)
{
    __shared__ ushort SH[32768];        // 64KB staging; TS[128][136] overlays post-loop
    ushort* TS = SH;

    const int tid = threadIdx.x;
    const int lane = tid & 63;
    const int wid = tid >> 6;
    const int wm = wid >> 1;            // 0..1
    const int wn = wid & 1;             // 0..1
    const int rowBase = blockIdx.x * 128;

    int mode, colBase;
    if (MODE_BASE == 3) { mode = 3; colBase = blockIdx.y * 128; }
    else { mode = blockIdx.y >> 2; colBase = (blockIdx.y & 3) * 128; }

    const ushort* __restrict__ W =
        (mode == 0) ? wq : (mode == 1) ? wk : (mode == 2) ? wv : wo;
    const float* __restrict__ bias =
        (mode == 0) ? bq : (mode == 1) ? bk : (mode == 2) ? bv : bo;

    const int fr = lane & 15;
    const int g = lane >> 4;
    const int fr7 = fr & 7;
    const int sc_row = tid >> 3;        // 0..31
    const int sc_c16 = tid & 7;

    f32x4 acc[4][4];
#pragma unroll
    for (int m = 0; m < 4; ++m)
#pragma unroll
        for (int n = 0; n < 4; ++n)
            acc[m][n] = (f32x4){0.f, 0.f, 0.f, 0.f};

    auto STAGE = [&](int kt) {
        const int k0 = kt * 64;
        const int bufb = (kt & 1) * 16384;
#pragma unroll
        for (int i = 0; i < 4; ++i) {
            const int row = i * 32 + sc_row;
            const int srcc = (sc_c16 ^ (row & 7)) * 8;
            GLD16(&A[(size_t)(rowBase + row) * E_DIM + k0 + srcc],
                  &SH[bufb + row * 64 + sc_c16 * 8]);
        }
#pragma unroll
        for (int i = 0; i < 4; ++i) {
            const int row = i * 32 + sc_row;
            const int srcc = (sc_c16 ^ (row & 7)) * 8;
            GLD16(&W[(size_t)(colBase + row) * E_DIM + k0 + srcc],
                  &SH[bufb + 8192 + row * 64 + sc_c16 * 8]);
        }
    };

    STAGE(0);
    STAGE(1);
    asm volatile("s_waitcnt vmcnt(8)" ::: "memory");
    __builtin_amdgcn_sched_barrier(0);
    __builtin_amdgcn_s_barrier();
    __builtin_amdgcn_sched_barrier(0);

    const int kch0 = (g ^ fr7) * 8;
    const int kch1 = ((4 + g) ^ fr7) * 8;
    const int aroff = (wm * 64 + fr) * 64;
    const int broff = 8192 + (wn * 64 + fr) * 64;
    const int b = rowBase >> 12;
    const int lloc = rowBase & (L_SEQ - 1);

    for (int gt = 0; gt < 8; ++gt) {
        const int base = (gt & 1) * 16384;
        bf16x8 af[2][4], bfv[2][4];
#pragma unroll
        for (int m = 0; m < 4; ++m) {
            af[0][m] = *reinterpret_cast<const bf16x8*>(&SH[base + aroff + m * 1024 + kch0]);
            af[1][m] = *reinterpret_cast<const bf16x8*>(&SH[base + aroff + m * 1024 + kch1]);
        }
#pragma unroll
        for (int n = 0; n < 4; ++n) {
            bfv[0][n] = *reinterpret_cast<const bf16x8*>(&SH[base + broff + n * 1024 + kch0]);
            bfv[1][n] = *reinterpret_cast<const bf16x8*>(&SH[base + broff + n * 1024 + kch1]);
        }
        BAR_LGKM();

        if (gt + 2 < 8) STAGE(gt + 2);

        __builtin_amdgcn_s_setprio(1);
#pragma unroll
        for (int kk = 0; kk < 2; ++kk)
#pragma unroll
            for (int m = 0; m < 4; ++m)
#pragma unroll
                for (int n = 0; n < 4; ++n)
                    acc[m][n] = __builtin_amdgcn_mfma_f32_16x16x32_bf16(
                        af[kk][m], bfv[kk][n], acc[m][n], 0, 0, 0);
        __builtin_amdgcn_s_setprio(0);
        __builtin_amdgcn_sched_barrier(0);

        if (gt < 7) {
            if (gt + 2 < 8) asm volatile("s_waitcnt vmcnt(8)" ::: "memory");
            else            asm volatile("s_waitcnt vmcnt(0)" ::: "memory");
            __builtin_amdgcn_sched_barrier(0);
            __builtin_amdgcn_s_barrier();
            __builtin_amdgcn_sched_barrier(0);
        }
    }

    // ---------------- epilogues ----------------
    if (mode == 0) {
#pragma unroll
        for (int m = 0; m < 4; ++m)
#pragma unroll
            for (int j = 0; j < 4; ++j) {
                const int grow = rowBase + wm * 64 + m * 16 + g * 4 + j;
#pragma unroll
                for (int n = 0; n < 4; ++n) {
                    const int gcol = colBase + wn * 64 + n * 16 + fr;
                    const float val = fmaxf(acc[m][n][j] + bias[gcol], 0.f);
                    qb[(size_t)grow * E_DIM + gcol] = f2bf(val);
                }
            }
    } else if (mode == 3) {
#pragma unroll
        for (int m = 0; m < 4; ++m)
#pragma unroll
            for (int j = 0; j < 4; ++j) {
                const int grow = rowBase + wm * 64 + m * 16 + g * 4 + j;
#pragma unroll
                for (int n = 0; n < 4; ++n) {
                    const int gcol = colBase + wn * 64 + n * 16 + fr;
                    outF[(size_t)grow * E_DIM + gcol] = acc[m][n][j] + bias[gcol];
                }
            }
    } else {
        ushort* __restrict__ dstbuf = (mode == 1) ? kT : vT;
        __syncthreads();                 // all waves done with SH buffers
#pragma unroll
        for (int m = 0; m < 4; ++m)
#pragma unroll
            for (int j = 0; j < 4; ++j) {
                const int lr_ = wm * 64 + m * 16 + g * 4 + j;
#pragma unroll
                for (int n = 0; n < 4; ++n) {
                    const int fcl = wn * 64 + n * 16 + fr;
                    float val = acc[m][n][j] + bias[colBase + fcl];
                    if (mode == 1) val = fmaxf(val, 0.f);
                    TS[fcl * 136 + lr_] = f2bf(val);
                }
            }
        __syncthreads();
#pragma unroll
        for (int i = 0; i < 8; ++i) {
            const int c = i * 256 + tid;
            const int r = c >> 4;              // local feature 0..127
            const int cc = c & 15;             // 16B chunk along l
            const size_t dst = ((size_t)(b * E_DIM + colBase + r)) * L_SEQ + lloc + cc * 8;
            *reinterpret_cast<uint4*>(&dstbuf[dst]) =
                *reinterpret_cast<const uint4*>(&TS[r * 136 + cc * 8]);
        }
    }
}

// ---------------- kv via MFMA, fused cos/sin from tables, no LDS ----------------
__global__ __launch_bounds__(256) void kv_kernel(
    const ushort* __restrict__ kT, const ushort* __restrict__ vT,
    const float* __restrict__ sintab, const float* __restrict__ costab,
    float* __restrict__ kv_part, float* __restrict__ sum_part)
{
    const int chunk = blockIdx.x;   // 0..7
    const int bh = blockIdx.y;      // 0..31
    const int tid = threadIdx.x;
    const int lane = tid & 63;
    const int w = tid >> 6;
    const int fr = lane & 15;
    const int g = lane >> 4;

    const size_t tbase = (size_t)bh * 64 * L_SEQ;

    f32x4 acc[8], accS[8];
#pragma unroll
    for (int n = 0; n < 8; ++n) {
        acc[n] = (f32x4){0.f, 0.f, 0.f, 0.f};
        accS[n] = (f32x4){0.f, 0.f, 0.f, 0.f};
    }

    const int lchunk = chunk * (L_SEQ / 8);
    for (int l0 = lchunk; l0 < lchunk + (L_SEQ / 8); l0 += 32) {
        const int col = l0 + g * 8;
        bf16x8 vf = *reinterpret_cast<const bf16x8*>(&vT[tbase + (size_t)(w * 16 + fr) * L_SEQ + col]);
        bf16x8 kf[4];
#pragma unroll
        for (int n = 0; n < 4; ++n)
            kf[n] = *reinterpret_cast<const bf16x8*>(&kT[tbase + (size_t)(n * 16 + fr) * L_SEQ + col]);
        float4 c0 = *reinterpret_cast<const float4*>(&costab[col]);
        float4 c1 = *reinterpret_cast<const float4*>(&costab[col + 4]);
        float4 s0 = *reinterpret_cast<const float4*>(&sintab[col]);
        float4 s1 = *reinterpret_cast<const float4*>(&sintab[col + 4]);
        const float c8[8] = {c0.x, c0.y, c0.z, c0.w, c1.x, c1.y, c1.z, c1.w};
        const float s8[8] = {s0.x, s0.y, s0.z, s0.w, s1.x, s1.y, s1.z, s1.w};
        bf16x8 afc, afs, cw, sw;
#pragma unroll
        for (int e = 0; e < 8; ++e) {
            const float v = bf2f((ushort)vf[e]);
            afc[e] = (short)f2bf(v * c8[e]);
            afs[e] = (short)f2bf(v * s8[e]);
            cw[e]  = (short)f2bf(c8[e]);
            sw[e]  = (short)f2bf(s8[e]);
        }
#pragma unroll
        for (int n = 0; n < 4; ++n) {
            acc[n]      = __builtin_amdgcn_mfma_f32_16x16x32_bf16(afc, kf[n], acc[n], 0, 0, 0);
            acc[n + 4]  = __builtin_amdgcn_mfma_f32_16x16x32_bf16(afs, kf[n], acc[n + 4], 0, 0, 0);
            accS[n]     = __builtin_amdgcn_mfma_f32_16x16x32_bf16(cw,  kf[n], accS[n], 0, 0, 0);
            accS[n + 4] = __builtin_amdgcn_mfma_f32_16x16x32_bf16(sw,  kf[n], accS[n + 4], 0, 0, 0);
        }
    }

    const size_t pbase = ((size_t)(chunk * 32 + bh)) * 8192;
#pragma unroll
    for (int n = 0; n < 8; ++n)
#pragma unroll
        for (int j = 0; j < 4; ++j)
            kv_part[pbase + (size_t)(w * 16 + g * 4 + j) * 128 + n * 16 + fr] = acc[n][j];
    if (w == 0 && g == 0) {
        const size_t sbase = (size_t)(chunk * 32 + bh) * 128;
#pragma unroll
        for (int n = 0; n < 8; ++n)
            sum_part[sbase + n * 16 + fr] = accS[n][0];
    }
}

// ---------------- reduce partials; emit bf16 kvT_ext[bh][80][128] ----------------
#define KVT_ROWS 80
#define KVT_STRIDE (KVT_ROWS * 128)
__global__ __launch_bounds__(256) void kv_reduce_kernel(
    const float* __restrict__ kv_part, const float* __restrict__ sum_part,
    ushort* __restrict__ kvT)
{
    const int bh = blockIdx.x;
    const int tid = threadIdx.x;
    ushort* kvb = kvT + (size_t)bh * KVT_STRIDE;
    for (int idx = tid; idx < 8192; idx += 256) {
        float s = 0.f;
#pragma unroll
        for (int c = 0; c < 8; ++c)
            s += kv_part[((size_t)(c * 32 + bh)) * 8192 + idx];
        kvb[idx] = f2bf(s);
    }
    if (tid < 128) {
        float s = 0.f;
#pragma unroll
        for (int c = 0; c < 8; ++c)
            s += sum_part[(size_t)(c * 32 + bh) * 128 + tid];
        const ushort hi = f2bf(s);
        const float lo = s - bf2f(hi);
        kvb[64 * 128 + tid] = hi;
        kvb[65 * 128 + tid] = f2bf(lo);
    }
    for (int idx = tid; idx < 14 * 128; idx += 256)
        kvb[66 * 128 + idx] = 0;
}

// ---------------- attention via MFMA: A-fragments scaled by cos/sin on the fly -------
__global__ __launch_bounds__(256) void attn_kernel(
    const ushort* __restrict__ Qb, const ushort* __restrict__ kvT,
    const float* __restrict__ sintab, const float* __restrict__ costab,
    ushort* __restrict__ attn_out)
{
    const int bh = blockIdx.y;
    const int b = bh >> 3, h = bh & 7;
    const int tid = threadIdx.x;
    const int lane = tid & 63;
    const int w = tid >> 6;

    __shared__ ushort Bs[KVT_ROWS][136];

#pragma unroll
    for (int i = 0; i < 5; ++i) {
        const int c = i * 256 + tid;
        const int d = c >> 4, cc = c & 15;
        *reinterpret_cast<uint4*>(&Bs[d][cc * 8]) =
            *reinterpret_cast<const uint4*>(&kvT[(size_t)bh * KVT_STRIDE + (size_t)c * 8]);
    }
    __syncthreads();

    const int rowBase = blockIdx.x * 256 + w * 64;
    const int fr = lane & 15;
    const int g = lane >> 4;

    float cvm[4], svm[4];
#pragma unroll
    for (int m = 0; m < 4; ++m) {
        const int l = (rowBase + m * 16 + fr) & (L_SEQ - 1);
        cvm[m] = costab[l];
        svm[m] = sintab[l];
    }

    f32x4 acc[4][5];
#pragma unroll
    for (int m = 0; m < 4; ++m)
#pragma unroll
        for (int n = 0; n < 5; ++n)
            acc[m][n] = (f32x4){0.f, 0.f, 0.f, 0.f};

#pragma unroll
    for (int ks = 0; ks < 4; ++ks) {
        const int kk = (ks & 1) * 32 + g * 8;
        const int kcomb = ks * 32 + g * 8;

        bf16x8 af[4];
#pragma unroll
        for (int m = 0; m < 4; ++m) {
            const int r = rowBase + m * 16 + fr;
            bf16x8 qf = *reinterpret_cast<const bf16x8*>(
                &Qb[((size_t)(b * L_SEQ) + r) * E_DIM + h * DHEAD + kk]);
            const float sc = (ks < 2) ? cvm[m] : svm[m];
#pragma unroll
            for (int e = 0; e < 8; ++e)
                af[m][e] = (short)f2bf(bf2f((ushort)qf[e]) * sc);
        }

        bf16x8 bfr[5];
#pragma unroll
        for (int n = 0; n < 5; ++n)
            bfr[n] = *reinterpret_cast<const bf16x8*>(&Bs[n * 16 + fr][kcomb]);
#pragma unroll
        for (int m = 0; m < 4; ++m)
#pragma unroll
            for (int n = 0; n < 5; ++n)
                acc[m][n] = __builtin_amdgcn_mfma_f32_16x16x32_bf16(af[m], bfr[n], acc[m][n], 0, 0, 0);
    }

#pragma unroll
    for (int m = 0; m < 4; ++m) {
#pragma unroll
        for (int j = 0; j < 4; ++j) {
            const float den = __shfl(acc[m][4][j], g * 16 + 0) + __shfl(acc[m][4][j], g * 16 + 1);
            const float z = 1.f / fmaxf(den, 1e-6f);
            const int grow = rowBase + m * 16 + g * 4 + j;
            const size_t obase = ((size_t)(b * L_SEQ) + grow) * E_DIM + h * DHEAD;
#pragma unroll
            for (int n = 0; n < 4; ++n)
                attn_out[obase + n * 16 + fr] = f2bf(acc[m][n][j] * z);
        }
    }
}

// ---------------- launch ----------------
extern "C" void kernel_launch(void* const* d_in, const int* in_sizes, int n_in,
                              void* d_out, int out_size, void* d_ws, size_t ws_size,
                              hipStream_t stream) {
    const float* x  = (const float*)d_in[0];
    const float* Wq = (const float*)d_in[1];
    const float* bq = (const float*)d_in[2];
    const float* Wk = (const float*)d_in[3];
    const float* bk = (const float*)d_in[4];
    const float* Wv = (const float*)d_in[5];
    const float* bv = (const float*)d_in[6];
    const float* Wo = (const float*)d_in[7];
    const float* bo = (const float*)d_in[8];
    float* out = (float*)d_out;

    char* ws = (char*)d_ws;
    size_t off = 0;
    auto alloc = [&](size_t bytes) -> char* {
        char* p = ws + off;
        off += (bytes + 255) & ~(size_t)255;
        return p;
    };

    const size_t big = (size_t)NROWS * E_DIM * sizeof(ushort);   // 16.8 MB
    ushort* xb  = (ushort*)alloc(big);
    ushort* wqb = (ushort*)alloc(512 * 512 * sizeof(ushort));
    ushort* wkb = (ushort*)alloc(512 * 512 * sizeof(ushort));
    ushort* wvb = (ushort*)alloc(512 * 512 * sizeof(ushort));
    ushort* wob = (ushort*)alloc(512 * 512 * sizeof(ushort));
    ushort* qb  = (ushort*)alloc(big);   // relu(q), [l][e]
    ushort* kT  = (ushort*)alloc(big);   // relu(k) transposed [bh][k][l]
    ushort* vT  = (ushort*)alloc(big);   // v transposed [bh][d][l]
    float* kv_part  = (float*)alloc((size_t)8 * 32 * 8192 * sizeof(float));
    float* sum_part = (float*)alloc((size_t)8 * 32 * 128 * sizeof(float));
    ushort* kvT     = (ushort*)alloc((size_t)32 * KVT_STRIDE * sizeof(ushort));
    float* sintab   = (float*)alloc(L_SEQ * sizeof(float));
    float* costab   = (float*)alloc(L_SEQ * sizeof(float));
    ushort* attnb = kT;  // kT consumed by kv_kernel before attn_kernel writes

    convert_all_kernel<<<3088, 256, 0, stream>>>(
        x, xb, Wq, Wk, Wv, Wo, wqb, wkb, wvb, wob, sintab, costab);

    // QKV: mode-major grid, 1536 blocks, 2 blocks/CU -> 3 exact rounds
    gemm6_kernel<0><<<dim3(128, 12), 256, 0, stream>>>(
        xb, wqb, wkb, wvb, wob, bq, bk, bv, bo, qb, kT, vT, nullptr);

    kv_kernel<<<dim3(8, 32), 256, 0, stream>>>(kT, vT, sintab, costab, kv_part, sum_part);
    kv_reduce_kernel<<<32, 256, 0, stream>>>(kv_part, sum_part, kvT);

    attn_kernel<<<dim3(16, 32), 256, 0, stream>>>(qb, kvT, sintab, costab, attnb);

    // out GEMM: 512 blocks = 1 round at 2 blocks/CU
    gemm6_kernel<3><<<dim3(128, 4), 256, 0, stream>>>(
        attnb, wqb, wkb, wvb, wob, bq, bk, bv, bo, nullptr, nullptr, nullptr, out);
}

// Round 16
// 95.509 us; speedup vs baseline: 1.1111x; 1.0016x over previous
//
#include <hip/hip_runtime.h>
#include <hip/hip_bf16.h>

#define L_SEQ 4096
#define E_DIM 512
#define NHEAD 8
#define DHEAD 64
#define NBATCH 4
#define NROWS (NBATCH * L_SEQ)   // 16384

typedef short bf16x8 __attribute__((ext_vector_type(8)));
typedef float f32x4 __attribute__((ext_vector_type(4)));

__device__ __forceinline__ float bf2f(ushort u) {
    union { float f; unsigned int i; } x;
    x.i = ((unsigned int)u) << 16;
    return x.f;
}
__device__ __forceinline__ ushort f2bf(float f) {
    unsigned int u = __float_as_uint(f);
    unsigned int r = 0x7fffu + ((u >> 16) & 1u);
    u += r;
    return (ushort)(u >> 16);
}

#define GLD16(gptr, lptr) \
    __builtin_amdgcn_global_load_lds( \
        (const __attribute__((address_space(1))) void*)(gptr), \
        (__attribute__((address_space(3))) void*)(lptr), 16, 0, 0)

#define BAR_LGKM() do { \
    asm volatile("s_waitcnt lgkmcnt(0)" ::: "memory"); \
    __builtin_amdgcn_sched_barrier(0); \
    __builtin_amdgcn_s_barrier(); \
    __builtin_amdgcn_sched_barrier(0); } while (0)

// ---------------- fused conversions: x -> bf16, W -> bf16, sin/cos tables ----------
__global__ __launch_bounds__(256) void convert_all_kernel(
    const float* __restrict__ x, ushort* __restrict__ xb,
    const float* __restrict__ w0, const float* __restrict__ w1,
    const float* __restrict__ w2, const float* __restrict__ w3,
    ushort* __restrict__ o0, ushort* __restrict__ o1,
    ushort* __restrict__ o2, ushort* __restrict__ o3,
    float* __restrict__ sintab, float* __restrict__ costab)
{
    const int tid = threadIdx.x;
    const int bid = blockIdx.x;
    if (bid < 2048) {
        const int n4 = NROWS * E_DIM / 4;
        for (int i = bid * 256 + tid; i < n4; i += 2048 * 256) {
            float4 f = reinterpret_cast<const float4*>(x)[i];
            ushort4 o;
            o.x = f2bf(f.x); o.y = f2bf(f.y); o.z = f2bf(f.z); o.w = f2bf(f.w);
            reinterpret_cast<ushort4*>(xb)[i] = o;
        }
    } else if (bid < 3072) {
        const int wb = bid - 2048;
        const int y = wb >> 8;
        const int i = (wb & 255) * 256 + tid;
        const float* in = (y == 0) ? w0 : (y == 1) ? w1 : (y == 2) ? w2 : w3;
        ushort* out = (y == 0) ? o0 : (y == 1) ? o1 : (y == 2) ? o2 : o3;
        float4 f = reinterpret_cast<const float4*>(in)[i];
        ushort4 o;
        o.x = f2bf(f.x); o.y = f2bf(f.y); o.z = f2bf(f.z); o.w = f2bf(f.w);
        reinterpret_cast<ushort4*>(out)[i] = o;
    } else {
        const int l = (bid - 3072) * 256 + tid;
        const float ang = (float)(l + 1) * (1.5707963267948966f / (float)L_SEQ);
        sintab[l] = sinf(ang);
        costab[l] = cosf(ang);
    }
}

// ---------------- pipelined GEMM: 128x128 tile, BK=64, dbuf, 2 blocks/CU ----------
// (r12-verified structure — session best.)
template<int MODE_BASE>
__global__ __launch_bounds__(256, 2) void gemm6_kernel(
    const ushort* __restrict__ A,
    const ushort* __restrict__ wq, const ushort* __restrict__ wk,
    const ushort* __restrict__ wv, const ushort* __restrict__ wo,
    const float* __restrict__ bq, const float* __restrict__ bk,
    const float* __restrict__ bv, const float* __restrict__ bo,
    ushort* __restrict__ qb, ushort* __restrict__ kT, ushort* __restrict__ vT,
    float* __restrict__ outF)
{
    __shared__ ushort SH[32768];        // 64KB staging; TS[128][136] overlays post-loop
    ushort* TS = SH;

    const int tid = threadIdx.x;
    const int lane = tid & 63;
    const int wid = tid >> 6;
    const int wm = wid >> 1;
    const int wn = wid & 1;
    const int rowBase = blockIdx.x * 128;

    int mode, colBase;
    if (MODE_BASE == 3) { mode = 3; colBase = blockIdx.y * 128; }
    else { mode = blockIdx.y >> 2; colBase = (blockIdx.y & 3) * 128; }

    const ushort* __restrict__ W =
        (mode == 0) ? wq : (mode == 1) ? wk : (mode == 2) ? wv : wo;
    const float* __restrict__ bias =
        (mode == 0) ? bq : (mode == 1) ? bk : (mode == 2) ? bv : bo;

    const int fr = lane & 15;
    const int g = lane >> 4;
    const int fr7 = fr & 7;
    const int sc_row = tid >> 3;
    const int sc_c16 = tid & 7;

    f32x4 acc[4][4];
#pragma unroll
    for (int m = 0; m < 4; ++m)
#pragma unroll
        for (int n = 0; n < 4; ++n)
            acc[m][n] = (f32x4){0.f, 0.f, 0.f, 0.f};

    auto STAGE = [&](int kt) {
        const int k0 = kt * 64;
        const int bufb = (kt & 1) * 16384;
#pragma unroll
        for (int i = 0; i < 4; ++i) {
            const int row = i * 32 + sc_row;
            const int srcc = (sc_c16 ^ (row & 7)) * 8;
            GLD16(&A[(size_t)(rowBase + row) * E_DIM + k0 + srcc],
                  &SH[bufb + row * 64 + sc_c16 * 8]);
        }
#pragma unroll
        for (int i = 0; i < 4; ++i) {
            const int row = i * 32 + sc_row;
            const int srcc = (sc_c16 ^ (row & 7)) * 8;
            GLD16(&W[(size_t)(colBase + row) * E_DIM + k0 + srcc],
                  &SH[bufb + 8192 + row * 64 + sc_c16 * 8]);
        }
    };

    STAGE(0);
    STAGE(1);
    asm volatile("s_waitcnt vmcnt(8)" ::: "memory");
    __builtin_amdgcn_sched_barrier(0);
    __builtin_amdgcn_s_barrier();
    __builtin_amdgcn_sched_barrier(0);

    const int kch0 = (g ^ fr7) * 8;
    const int kch1 = ((4 + g) ^ fr7) * 8;
    const int aroff = (wm * 64 + fr) * 64;
    const int broff = 8192 + (wn * 64 + fr) * 64;
    const int b = rowBase >> 12;
    const int lloc = rowBase & (L_SEQ - 1);

    for (int gt = 0; gt < 8; ++gt) {
        const int base = (gt & 1) * 16384;
        bf16x8 af[2][4], bfv[2][4];
#pragma unroll
        for (int m = 0; m < 4; ++m) {
            af[0][m] = *reinterpret_cast<const bf16x8*>(&SH[base + aroff + m * 1024 + kch0]);
            af[1][m] = *reinterpret_cast<const bf16x8*>(&SH[base + aroff + m * 1024 + kch1]);
        }
#pragma unroll
        for (int n = 0; n < 4; ++n) {
            bfv[0][n] = *reinterpret_cast<const bf16x8*>(&SH[base + broff + n * 1024 + kch0]);
            bfv[1][n] = *reinterpret_cast<const bf16x8*>(&SH[base + broff + n * 1024 + kch1]);
        }
        BAR_LGKM();

        if (gt + 2 < 8) STAGE(gt + 2);

        __builtin_amdgcn_s_setprio(1);
#pragma unroll
        for (int kk = 0; kk < 2; ++kk)
#pragma unroll
            for (int m = 0; m < 4; ++m)
#pragma unroll
                for (int n = 0; n < 4; ++n)
                    acc[m][n] = __builtin_amdgcn_mfma_f32_16x16x32_bf16(
                        af[kk][m], bfv[kk][n], acc[m][n], 0, 0, 0);
        __builtin_amdgcn_s_setprio(0);
        __builtin_amdgcn_sched_barrier(0);

        if (gt < 7) {
            if (gt + 2 < 8) asm volatile("s_waitcnt vmcnt(8)" ::: "memory");
            else            asm volatile("s_waitcnt vmcnt(0)" ::: "memory");
            __builtin_amdgcn_sched_barrier(0);
            __builtin_amdgcn_s_barrier();
            __builtin_amdgcn_sched_barrier(0);
        }
    }

    // ---------------- epilogues ----------------
    if (mode == 0) {
#pragma unroll
        for (int m = 0; m < 4; ++m)
#pragma unroll
            for (int j = 0; j < 4; ++j) {
                const int grow = rowBase + wm * 64 + m * 16 + g * 4 + j;
#pragma unroll
                for (int n = 0; n < 4; ++n) {
                    const int gcol = colBase + wn * 64 + n * 16 + fr;
                    const float val = fmaxf(acc[m][n][j] + bias[gcol], 0.f);
                    qb[(size_t)grow * E_DIM + gcol] = f2bf(val);
                }
            }
    } else if (mode == 3) {
#pragma unroll
        for (int m = 0; m < 4; ++m)
#pragma unroll
            for (int j = 0; j < 4; ++j) {
                const int grow = rowBase + wm * 64 + m * 16 + g * 4 + j;
#pragma unroll
                for (int n = 0; n < 4; ++n) {
                    const int gcol = colBase + wn * 64 + n * 16 + fr;
                    outF[(size_t)grow * E_DIM + gcol] = acc[m][n][j] + bias[gcol];
                }
            }
    } else {
        ushort* __restrict__ dstbuf = (mode == 1) ? kT : vT;
        __syncthreads();
#pragma unroll
        for (int m = 0; m < 4; ++m)
#pragma unroll
            for (int j = 0; j < 4; ++j) {
                const int lr_ = wm * 64 + m * 16 + g * 4 + j;
#pragma unroll
                for (int n = 0; n < 4; ++n) {
                    const int fcl = wn * 64 + n * 16 + fr;
                    float val = acc[m][n][j] + bias[colBase + fcl];
                    if (mode == 1) val = fmaxf(val, 0.f);
                    TS[fcl * 136 + lr_] = f2bf(val);
                }
            }
        __syncthreads();
#pragma unroll
        for (int i = 0; i < 8; ++i) {
            const int c = i * 256 + tid;
            const int r = c >> 4;
            const int cc = c & 15;
            const size_t dst = ((size_t)(b * E_DIM + colBase + r)) * L_SEQ + lloc + cc * 8;
            *reinterpret_cast<uint4*>(&dstbuf[dst]) =
                *reinterpret_cast<const uint4*>(&TS[r * 136 + cc * 8]);
        }
    }
}

// ---------------- kv via MFMA, fused cos/sin from tables, no LDS ----------------
__global__ __launch_bounds__(256) void kv_kernel(
    const ushort* __restrict__ kT, const ushort* __restrict__ vT,
    const float* __restrict__ sintab, const float* __restrict__ costab,
    float* __restrict__ kv_part, float* __restrict__ sum_part)
{
    const int chunk = blockIdx.x;   // 0..7
    const int bh = blockIdx.y;      // 0..31
    const int tid = threadIdx.x;
    const int lane = tid & 63;
    const int w = tid >> 6;
    const int fr = lane & 15;
    const int g = lane >> 4;

    const size_t tbase = (size_t)bh * 64 * L_SEQ;

    f32x4 acc[8], accS[8];
#pragma unroll
    for (int n = 0; n < 8; ++n) {
        acc[n] = (f32x4){0.f, 0.f, 0.f, 0.f};
        accS[n] = (f32x4){0.f, 0.f, 0.f, 0.f};
    }

    const int lchunk = chunk * (L_SEQ / 8);
    for (int l0 = lchunk; l0 < lchunk + (L_SEQ / 8); l0 += 32) {
        const int col = l0 + g * 8;
        bf16x8 vf = *reinterpret_cast<const bf16x8*>(&vT[tbase + (size_t)(w * 16 + fr) * L_SEQ + col]);
        bf16x8 kf[4];
#pragma unroll
        for (int n = 0; n < 4; ++n)
            kf[n] = *reinterpret_cast<const bf16x8*>(&kT[tbase + (size_t)(n * 16 + fr) * L_SEQ + col]);
        float4 c0 = *reinterpret_cast<const float4*>(&costab[col]);
        float4 c1 = *reinterpret_cast<const float4*>(&costab[col + 4]);
        float4 s0 = *reinterpret_cast<const float4*>(&sintab[col]);
        float4 s1 = *reinterpret_cast<const float4*>(&sintab[col + 4]);
        const float c8[8] = {c0.x, c0.y, c0.z, c0.w, c1.x, c1.y, c1.z, c1.w};
        const float s8[8] = {s0.x, s0.y, s0.z, s0.w, s1.x, s1.y, s1.z, s1.w};
        bf16x8 afc, afs, cw, sw;
#pragma unroll
        for (int e = 0; e < 8; ++e) {
            const float v = bf2f((ushort)vf[e]);
            afc[e] = (short)f2bf(v * c8[e]);
            afs[e] = (short)f2bf(v * s8[e]);
            cw[e]  = (short)f2bf(c8[e]);
            sw[e]  = (short)f2bf(s8[e]);
        }
#pragma unroll
        for (int n = 0; n < 4; ++n) {
            acc[n]      = __builtin_amdgcn_mfma_f32_16x16x32_bf16(afc, kf[n], acc[n], 0, 0, 0);
            acc[n + 4]  = __builtin_amdgcn_mfma_f32_16x16x32_bf16(afs, kf[n], acc[n + 4], 0, 0, 0);
            accS[n]     = __builtin_amdgcn_mfma_f32_16x16x32_bf16(cw,  kf[n], accS[n], 0, 0, 0);
            accS[n + 4] = __builtin_amdgcn_mfma_f32_16x16x32_bf16(sw,  kf[n], accS[n + 4], 0, 0, 0);
        }
    }

    const size_t pbase = ((size_t)(chunk * 32 + bh)) * 8192;
#pragma unroll
    for (int n = 0; n < 8; ++n)
#pragma unroll
        for (int j = 0; j < 4; ++j)
            kv_part[pbase + (size_t)(w * 16 + g * 4 + j) * 128 + n * 16 + fr] = acc[n][j];
    if (w == 0 && g == 0) {
        const size_t sbase = (size_t)(chunk * 32 + bh) * 128;
#pragma unroll
        for (int n = 0; n < 8; ++n)
            sum_part[sbase + n * 16 + fr] = accS[n][0];
    }
}

// ---------------- attention: reduces kv partials in-block, MFMA numerator+den -------
#define KVT_ROWS 80
__global__ __launch_bounds__(256) void attn_kernel(
    const ushort* __restrict__ Qb,
    const float* __restrict__ kv_part, const float* __restrict__ sum_part,
    const float* __restrict__ sintab, const float* __restrict__ costab,
    ushort* __restrict__ attn_out)
{
    const int bh = blockIdx.y;
    const int b = bh >> 3, h = bh & 7;
    const int tid = threadIdx.x;
    const int lane = tid & 63;
    const int w = tid >> 6;

    __shared__ ushort Bs[KVT_ROWS][136];

    // reduce the 8 fp32 partial chunks for this bh directly into Bs (c-order preserved
    // -> bit-identical to the old kv_reduce path)
#pragma unroll
    for (int i = 0; i < 32; ++i) {
        const int idx = i * 256 + tid;
        float s = 0.f;
#pragma unroll
        for (int c = 0; c < 8; ++c)
            s += kv_part[((size_t)(c * 32 + bh)) * 8192 + idx];
        Bs[idx >> 7][idx & 127] = f2bf(s);
    }
    if (tid < 128) {
        float s = 0.f;
#pragma unroll
        for (int c = 0; c < 8; ++c)
            s += sum_part[(size_t)(c * 32 + bh) * 128 + tid];
        const ushort hi = f2bf(s);
        const float lo = s - bf2f(hi);
        Bs[64][tid] = hi;
        Bs[65][tid] = f2bf(lo);
    }
    for (int idx = tid; idx < 14 * 128; idx += 256)
        Bs[66 + (idx >> 7)][idx & 127] = 0;
    __syncthreads();

    const int rowBase = blockIdx.x * 256 + w * 64;
    const int fr = lane & 15;
    const int g = lane >> 4;

    float cvm[4], svm[4];
#pragma unroll
    for (int m = 0; m < 4; ++m) {
        const int l = (rowBase + m * 16 + fr) & (L_SEQ - 1);
        cvm[m] = costab[l];
        svm[m] = sintab[l];
    }

    f32x4 acc[4][5];
#pragma unroll
    for (int m = 0; m < 4; ++m)
#pragma unroll
        for (int n = 0; n < 5; ++n)
            acc[m][n] = (f32x4){0.f, 0.f, 0.f, 0.f};

#pragma unroll
    for (int ks = 0; ks < 4; ++ks) {
        const int kk = (ks & 1) * 32 + g * 8;
        const int kcomb = ks * 32 + g * 8;

        bf16x8 af[4];
#pragma unroll
        for (int m = 0; m < 4; ++m) {
            const int r = rowBase + m * 16 + fr;
            bf16x8 qf = *reinterpret_cast<const bf16x8*>(
                &Qb[((size_t)(b * L_SEQ) + r) * E_DIM + h * DHEAD + kk]);
            const float sc = (ks < 2) ? cvm[m] : svm[m];
#pragma unroll
            for (int e = 0; e < 8; ++e)
                af[m][e] = (short)f2bf(bf2f((ushort)qf[e]) * sc);
        }

        bf16x8 bfr[5];
#pragma unroll
        for (int n = 0; n < 5; ++n)
            bfr[n] = *reinterpret_cast<const bf16x8*>(&Bs[n * 16 + fr][kcomb]);
#pragma unroll
        for (int m = 0; m < 4; ++m)
#pragma unroll
            for (int n = 0; n < 5; ++n)
                acc[m][n] = __builtin_amdgcn_mfma_f32_16x16x32_bf16(af[m], bfr[n], acc[m][n], 0, 0, 0);
    }

#pragma unroll
    for (int m = 0; m < 4; ++m) {
#pragma unroll
        for (int j = 0; j < 4; ++j) {
            const float den = __shfl(acc[m][4][j], g * 16 + 0) + __shfl(acc[m][4][j], g * 16 + 1);
            const float z = 1.f / fmaxf(den, 1e-6f);
            const int grow = rowBase + m * 16 + g * 4 + j;
            const size_t obase = ((size_t)(b * L_SEQ) + grow) * E_DIM + h * DHEAD;
#pragma unroll
            for (int n = 0; n < 4; ++n)
                attn_out[obase + n * 16 + fr] = f2bf(acc[m][n][j] * z);
        }
    }
}

// ---------------- launch ----------------
extern "C" void kernel_launch(void* const* d_in, const int* in_sizes, int n_in,
                              void* d_out, int out_size, void* d_ws, size_t ws_size,
                              hipStream_t stream) {
    const float* x  = (const float*)d_in[0];
    const float* Wq = (const float*)d_in[1];
    const float* bq = (const float*)d_in[2];
    const float* Wk = (const float*)d_in[3];
    const float* bk = (const float*)d_in[4];
    const float* Wv = (const float*)d_in[5];
    const float* bv = (const float*)d_in[6];
    const float* Wo = (const float*)d_in[7];
    const float* bo = (const float*)d_in[8];
    float* out = (float*)d_out;

    char* ws = (char*)d_ws;
    size_t off = 0;
    auto alloc = [&](size_t bytes) -> char* {
        char* p = ws + off;
        off += (bytes + 255) & ~(size_t)255;
        return p;
    };

    const size_t big = (size_t)NROWS * E_DIM * sizeof(ushort);   // 16.8 MB
    ushort* xb  = (ushort*)alloc(big);
    ushort* wqb = (ushort*)alloc(512 * 512 * sizeof(ushort));
    ushort* wkb = (ushort*)alloc(512 * 512 * sizeof(ushort));
    ushort* wvb = (ushort*)alloc(512 * 512 * sizeof(ushort));
    ushort* wob = (ushort*)alloc(512 * 512 * sizeof(ushort));
    ushort* qb  = (ushort*)alloc(big);   // relu(q), [l][e]
    ushort* kT  = (ushort*)alloc(big);   // relu(k) transposed [bh][k][l]
    ushort* vT  = (ushort*)alloc(big);   // v transposed [bh][d][l]
    float* kv_part  = (float*)alloc((size_t)8 * 32 * 8192 * sizeof(float));
    float* sum_part = (float*)alloc((size_t)8 * 32 * 128 * sizeof(float));
    float* sintab   = (float*)alloc(L_SEQ * sizeof(float));
    float* costab   = (float*)alloc(L_SEQ * sizeof(float));
    ushort* attnb = kT;  // kT consumed by kv_kernel before attn_kernel writes

    convert_all_kernel<<<3088, 256, 0, stream>>>(
        x, xb, Wq, Wk, Wv, Wo, wqb, wkb, wvb, wob, sintab, costab);

    // QKV: mode-major grid, 1536 blocks, 2 blocks/CU -> 3 exact rounds
    gemm6_kernel<0><<<dim3(128, 12), 256, 0, stream>>>(
        xb, wqb, wkb, wvb, wob, bq, bk, bv, bo, qb, kT, vT, nullptr);

    kv_kernel<<<dim3(8, 32), 256, 0, stream>>>(kT, vT, sintab, costab, kv_part, sum_part);

    // attn reduces kv partials in-block (kv_reduce fused away)
    attn_kernel<<<dim3(16, 32), 256, 0, stream>>>(
        qb, kv_part, sum_part, sintab, costab, attnb);

    // out GEMM: 512 blocks = 1 round at 2 blocks/CU
    gemm6_kernel<3><<<dim3(128, 4), 256, 0, stream>>>(
        attnb, wqb, wkb, wvb, wob, bq, bk, bv, bo, nullptr, nullptr, nullptr, out);
}